// Round 20
// baseline (239.680 us; speedup 1.0000x reference)
//
#include <hip/hip_runtime.h>
#include <hip/hip_bf16.h>
#include <math.h>

// ---------------- problem constants ----------------
#define BATCH   1024
#define NUMPT   100
#define NVAR    11
#define NOBS    10
#define HID     1024
#define INPD    55
#define TRAJD   200

#define T_FIN_C   15.0f
#define K_P_C     20.0f
#define K_D_C     8.944271909999159f   // 2*sqrt(20)
#define K_P_V_C   20.0f
#define A_OBS_C   8.0f
#define B_OBS_C   4.2f
#define AB_C      33.6f                 // A_OBS*B_OBS
#define ABSQ_C    1128.96f              // (A_OBS*B_OBS)^2
#define RHO_V_C      1.0f
#define RHO_PROJ_C   1.0f
#define RHO_LANE_C   100.0f
#define RHO_OBS_C    100.0f
#define RHO_OFFSET_C 1.0f
#define RHO_INEQ_C   100.0f
#define V_MIN_C   0.1f
#define V_MAX_C   30.0f
#define A_MAX_C   8.0f
#define MAXIT     20

// workspace layout (float offsets)
#define WS_INV1X  0      // 14x14
#define WS_INV1Y  256    // 15x15
#define WS_INV2X  512    // 14x14
#define WS_INV2Y  768    // 15x15
#define WS_SVD    1024   // 4x11 chunk-summed A_vd
#define WS_SPD    1088   // 4x11 chunk-summed A_pd
#define WS_QX     1152   // 11x11
#define WS_QY     1280   // 11x11
#define WS_R2X    1408   // 11x11  inv2x[:11,:11] @ Qx
#define WS_R2Y    1536   // 11x11
#define WS_BIG    2048

typedef __bf16 bf16x8 __attribute__((ext_vector_type(8)));
typedef float  f32x4  __attribute__((ext_vector_type(4)));

// ---------------------------------------------------------------------------
// Fused setup kernel (grid 4 + 1024 + 608) — R13/R16 verbatim.
// ---------------------------------------------------------------------------
__global__ __launch_bounds__(256) void setup_kernel(
    const float* __restrict__ Pg, const float* __restrict__ Pdg,
    const float* __restrict__ Pddg, float* __restrict__ ws,
    const float* __restrict__ inp, const float* __restrict__ traj,
    const float* __restrict__ mean, const float* __restrict__ stdv,
    __bf16* __restrict__ enc_in, __bf16* __restrict__ dec_in,
    const float* __restrict__ w1, const float* __restrict__ w2,
    const float* __restrict__ w3, const float* __restrict__ w4,
    __bf16* __restrict__ o1, __bf16* __restrict__ o2,
    __bf16* __restrict__ o3, __bf16* __restrict__ o4)
{
    __shared__ float sP[NUMPT*NVAR], sPd[NUMPT*NVAR], sPdd[NUMPT*NVAR];
    __shared__ float aug[15][31];
    __shared__ float fcol[15];
    __shared__ float sQ[121];
    __shared__ float sn[INPD];
    __shared__ float tile[64][65];
    __shared__ float s_pivinv;
    __shared__ int   s_pidx;
    const int tid = threadIdx.x, bid = blockIdx.x;

    if (bid >= 1028) {   // ------------- tiled weight transpose -------------
        const int tb = bid - 1028;
        int wsel, kt, nt;
        if (tb < 64)       { wsel = 0; kt = tb >> 4;        nt = tb & 15; }
        else if (tb < 320) { wsel = 1; kt = (tb-64) >> 4;   nt = (tb-64) & 15; }
        else if (tb < 352) { wsel = 2; kt = (tb-320) >> 4;  nt = (tb-320) & 15; }
        else               { wsel = 3; kt = (tb-352) >> 4;  nt = (tb-352) & 15; }
        const float* W = (wsel==0) ? w1 : (wsel==1) ? w2 : (wsel==2) ? w3 : w4;
        __bf16* O      = (wsel==0) ? o1 : (wsel==1) ? o2 : (wsel==2) ? o3 : o4;
        const int K  = (wsel==0) ? 255 : (wsel==2) ? 57 : 1024;
        const int Kp = (wsel==0) ? 256 : (wsel==2) ? 128 : 1024;
        if (kt*64 >= Kp) return;
        const int k0 = kt*64, n0 = nt*64;
        const int rr = tid >> 6, c = tid & 63;
        #pragma unroll 4
        for (int it = 0; it < 16; ++it) {
            const int r = it*4 + rr;
            tile[r][c] = (k0 + r < K) ? W[(size_t)(k0 + r)*HID + n0 + c] : 0.0f;
        }
        __syncthreads();
        #pragma unroll 4
        for (int it = 0; it < 16; ++it) {
            const int r = it*4 + rr;
            O[(size_t)(n0 + r)*Kp + k0 + c] = (__bf16)tile[c][r];
        }
        return;
    }

    if (bid >= 4) {      // ---------------- input prep ----------------
        const int b = bid - 4;
        if (tid < INPD) {
            const float v = (inp[b*INPD + tid] - mean[tid]) / stdv[tid];
            sn[tid] = v;
            enc_in[b*256 + tid] = (__bf16)v;
        } else if (tid < 255) {
            enc_in[b*256 + tid] = (__bf16)traj[b*TRAJD + (tid - INPD)];
        } else {
            enc_in[b*256 + 255] = (__bf16)0.0f;
        }
        __syncthreads();
        if (tid >= 2 && tid < 128)
            dec_in[b*128 + tid] = (__bf16)((tid < 57) ? sn[tid - 2] : 0.0f);
        return;
    }

    // ---------------- precompute (bid 0..3) ----------------
    for (int i = tid; i < NUMPT*NVAR; i += 256) {
        sP[i] = Pg[i]; sPd[i] = Pdg[i]; sPdd[i] = Pddg[i];
    }
    for (int i = tid; i < 15*31; i += 256) (&aug[0][0])[i] = 0.0f;
    __syncthreads();

    const int N = (bid == 0 || bid == 2) ? 14 : 15;

    if (tid < 121) {
        const int i = tid / 11, j = tid % 11;
        float s = 0.0f;
        if (bid == 0) {
            for (int t = 0; t < NUMPT; ++t) {
                float pdd_i = sPdd[t*NVAR+i], pdd_j = sPdd[t*NVAR+j];
                float av_i = pdd_i - K_P_V_C * sPd[t*NVAR+i];
                float av_j = pdd_j - K_P_V_C * sPd[t*NVAR+j];
                s += pdd_i*pdd_j + RHO_V_C * av_i*av_j;
            }
        } else if (bid == 1) {
            for (int t = 0; t < NUMPT; ++t) {
                float pdd_i = sPdd[t*NVAR+i], pdd_j = sPdd[t*NVAR+j];
                float ap_i = pdd_i - K_P_C*sP[t*NVAR+i] - K_D_C*sPd[t*NVAR+i];
                float ap_j = pdd_j - K_P_C*sP[t*NVAR+j] - K_D_C*sPd[t*NVAR+j];
                s += pdd_i*pdd_j + RHO_OFFSET_C * ap_i*ap_j;
            }
        } else {
            float obs_w = RHO_OBS_C * (float)NOBS;
            if (bid == 3) obs_w += RHO_LANE_C * 2.0f;
            for (int t = 0; t < NUMPT; ++t) {
                float p_i = sP[t*NVAR+i],   p_j = sP[t*NVAR+j];
                float pd_i = sPd[t*NVAR+i], pd_j = sPd[t*NVAR+j];
                float pdd_i = sPdd[t*NVAR+i], pdd_j = sPdd[t*NVAR+j];
                s += obs_w*p_i*p_j + RHO_INEQ_C*(pdd_i*pdd_j + pd_i*pd_j);
            }
            if (i == j) s += RHO_PROJ_C;
        }
        aug[i][j] = s;
    }
    if (tid < 11) {
        const int i = tid;
        float a0 = sP[i], a1 = sPd[i], a2 = sPdd[i];
        aug[i][11] = a0; aug[11][i] = a0;
        aug[i][12] = a1; aug[12][i] = a1;
        aug[i][13] = a2; aug[13][i] = a2;
        if (N == 15) { float a3 = sPd[99*NVAR + i]; aug[i][14] = a3; aug[14][i] = a3; }
    }
    if (tid < N) aug[tid][N + tid] = 1.0f;

    if (bid == 0 && tid < 44) {
        const int c = tid / 11, k = tid % 11;
        float sv = 0.0f, sp = 0.0f;
        for (int t = 25*c; t < 25*c + 25; ++t) {
            float p = sP[t*NVAR+k], pd = sPd[t*NVAR+k], pdd = sPdd[t*NVAR+k];
            sv += pdd - K_P_V_C * pd;
            sp += pdd - K_P_C * p - K_D_C * pd;
        }
        ws[WS_SVD + tid] = sv;
        ws[WS_SPD + tid] = sp;
    }
    __syncthreads();

    if ((bid == 2 || bid == 3) && tid < 121) {
        float v = aug[tid/11][tid%11];
        if (tid/11 == tid%11) v -= RHO_PROJ_C;
        sQ[tid] = v;
        ws[(bid == 2 ? WS_QX : WS_QY) + tid] = v;
    }

    for (int k = 0; k < N; ++k) {
        if (tid == 0) {
            int p = k; float best = fabsf(aug[k][k]);
            for (int i = k+1; i < N; ++i) {
                float v = fabsf(aug[i][k]);
                if (v > best) { best = v; p = i; }
            }
            s_pidx = p;
        }
        __syncthreads();
        const int p = s_pidx;
        if (p != k && tid < 2*N) {
            float tmp = aug[k][tid]; aug[k][tid] = aug[p][tid]; aug[p][tid] = tmp;
        }
        __syncthreads();
        if (tid == 0) s_pivinv = 1.0f / aug[k][k];
        __syncthreads();
        if (tid < 2*N) aug[k][tid] *= s_pivinv;
        __syncthreads();
        if (tid < N) fcol[tid] = (tid == k) ? 0.0f : aug[tid][k];
        __syncthreads();
        for (int idx = tid; idx < N*2*N; idx += 256) {
            const int i = idx / (2*N), j = idx % (2*N);
            if (i != k) aug[i][j] = fmaf(-fcol[i], aug[k][j], aug[i][j]);
        }
        __syncthreads();
    }

    float* dst = ws + (bid == 0 ? WS_INV1X : bid == 1 ? WS_INV1Y
                      : bid == 2 ? WS_INV2X : WS_INV2Y);
    for (int idx = tid; idx < N*N; idx += 256)
        dst[idx] = aug[idx / N][N + idx % N];
    __syncthreads();

    if ((bid == 2 || bid == 3) && tid < 121) {
        const int k = tid / 11, j = tid % 11;
        float a = 0.0f;
        #pragma unroll
        for (int m = 0; m < 11; ++m) a = fmaf(aug[k][N + m], sQ[m*11 + j], a);
        ws[(bid == 2 ? WS_R2X : WS_R2Y) + tid] = a;
    }
}

// ---------------------------------------------------------------------------
// Shared GEMM core, double-buffered LDS (R16 measured-best). 32x64 tile,
// BK=128, 4 waves. Grid (16,32) = 512 blocks -> 2 blocks/CU.
// __VA_ARGS__ = optional staging patch (k0 = 0 prologue only).
// ---------------------------------------------------------------------------
#define GEMM_CORE(A_, Wt_, Kp_, ...)                                          \
    __shared__ __bf16 As[2][32][136];                                         \
    __shared__ __bf16 Bs[2][64][136];                                         \
    const int lane = tid & 63, wv = tid >> 6;                                 \
    const int wm = (wv >> 1) * 16, wn = (wv & 1) * 32;                        \
    const int ln = lane & 15, q = lane >> 4;                                  \
    const int row0 = blockIdx.y * 32, col0 = blockIdx.x * 64;                 \
    const int r16 = tid >> 4, ch = (tid & 15) * 8;                            \
    f32x4 acc0 = (f32x4){0,0,0,0}, acc1 = (f32x4){0,0,0,0};                   \
    {                                                                         \
        bf16x8 va = *(const bf16x8*)&(A_)[(size_t)(row0 + r16)*(Kp_) + ch];   \
        bf16x8 vb = *(const bf16x8*)&(A_)[(size_t)(row0 + r16 + 16)*(Kp_) + ch]; \
        __VA_ARGS__                                                           \
        *(bf16x8*)&As[0][r16][ch] = va;                                       \
        *(bf16x8*)&As[0][r16 + 16][ch] = vb;                                  \
        _Pragma("unroll")                                                     \
        for (int p = 0; p < 4; ++p)                                           \
            *(bf16x8*)&Bs[0][r16 + 16*p][ch] =                                \
                *(const bf16x8*)&(Wt_)[(size_t)(col0 + r16 + 16*p)*(Kp_) + ch]; \
    }                                                                         \
    __syncthreads();                                                          \
    int cur = 0;                                                              \
    for (int k0 = 128; k0 < (Kp_); k0 += 128) {                               \
        const bf16x8 nva = *(const bf16x8*)&(A_)[(size_t)(row0 + r16)*(Kp_) + k0 + ch]; \
        const bf16x8 nvb = *(const bf16x8*)&(A_)[(size_t)(row0 + r16 + 16)*(Kp_) + k0 + ch]; \
        const bf16x8 nw0 = *(const bf16x8*)&(Wt_)[(size_t)(col0 + r16)*(Kp_) + k0 + ch]; \
        const bf16x8 nw1 = *(const bf16x8*)&(Wt_)[(size_t)(col0 + r16 + 16)*(Kp_) + k0 + ch]; \
        const bf16x8 nw2 = *(const bf16x8*)&(Wt_)[(size_t)(col0 + r16 + 32)*(Kp_) + k0 + ch]; \
        const bf16x8 nw3 = *(const bf16x8*)&(Wt_)[(size_t)(col0 + r16 + 48)*(Kp_) + k0 + ch]; \
        _Pragma("unroll")                                                     \
        for (int kc = 0; kc < 4; ++kc) {                                      \
            const bf16x8 a  = *(const bf16x8*)&As[cur][wm + ln][kc*32 + q*8]; \
            const bf16x8 b0 = *(const bf16x8*)&Bs[cur][wn + ln][kc*32 + q*8]; \
            const bf16x8 b1 = *(const bf16x8*)&Bs[cur][wn + 16 + ln][kc*32 + q*8]; \
            acc0 = __builtin_amdgcn_mfma_f32_16x16x32_bf16(a, b0, acc0, 0, 0, 0); \
            acc1 = __builtin_amdgcn_mfma_f32_16x16x32_bf16(a, b1, acc1, 0, 0, 0); \
        }                                                                     \
        const int nxt = cur ^ 1;                                              \
        *(bf16x8*)&As[nxt][r16][ch] = nva;                                    \
        *(bf16x8*)&As[nxt][r16 + 16][ch] = nvb;                               \
        *(bf16x8*)&Bs[nxt][r16][ch] = nw0;                                    \
        *(bf16x8*)&Bs[nxt][r16 + 16][ch] = nw1;                               \
        *(bf16x8*)&Bs[nxt][r16 + 32][ch] = nw2;                               \
        *(bf16x8*)&Bs[nxt][r16 + 48][ch] = nw3;                               \
        __syncthreads();                                                      \
        cur = nxt;                                                            \
    }                                                                         \
    _Pragma("unroll")                                                         \
    for (int kc = 0; kc < 4; ++kc) {                                          \
        const bf16x8 a  = *(const bf16x8*)&As[cur][wm + ln][kc*32 + q*8];     \
        const bf16x8 b0 = *(const bf16x8*)&Bs[cur][wn + ln][kc*32 + q*8];     \
        const bf16x8 b1 = *(const bf16x8*)&Bs[cur][wn + 16 + ln][kc*32 + q*8]; \
        acc0 = __builtin_amdgcn_mfma_f32_16x16x32_bf16(a, b0, acc0, 0, 0, 0); \
        acc1 = __builtin_amdgcn_mfma_f32_16x16x32_bf16(a, b1, acc1, 0, 0, 0); \
    }

#define GEMM_WRITE_RELU(C_)                                                   \
    _Pragma("unroll")                                                         \
    for (int ni = 0; ni < 2; ++ni) {                                          \
        const int col = col0 + wn + ni*16 + ln;                               \
        const float bv = bias[col];                                           \
        const f32x4 av = ni ? acc1 : acc0;                                    \
        _Pragma("unroll")                                                     \
        for (int r = 0; r < 4; ++r) {                                         \
            const int row = row0 + wm + q*4 + r;                              \
            (C_)[(size_t)row * HID + col] = (__bf16)fmaxf(av[r] + bv, 0.0f);  \
        }                                                                     \
    }

// ---------------------------------------------------------------------------
__global__ __launch_bounds__(256) void gemm_relu(
    const __bf16* __restrict__ A, const __bf16* __restrict__ Wt,
    const float* __restrict__ bias, __bf16* __restrict__ C, int Kp)
{
    const int tid = threadIdx.x;
    GEMM_CORE(A, Wt, Kp)
    GEMM_WRITE_RELU(C)
}

// ---------------------------------------------------------------------------
// gemm2: encoder layer 2 + fused mu/logvar PARTIAL dots -> pmulv[row][32][4].
// ---------------------------------------------------------------------------
__global__ __launch_bounds__(256) void gemm_mulv(
    const __bf16* __restrict__ A, const __bf16* __restrict__ Wt,
    const float* __restrict__ bias,
    const float* __restrict__ wmu, const float* __restrict__ wlv,
    float* __restrict__ pmulv, int Kp)
{
    const int tid = threadIdx.x;
    GEMM_CORE(A, Wt, Kp)
    const int c0 = col0 + wn + ln;
    const int c1 = c0 + 16;
    const float b0v = bias[c0], b1v = bias[c1];
    const float wm00 = wmu[c0*2+0], wm01 = wmu[c0*2+1];
    const float wm10 = wmu[c1*2+0], wm11 = wmu[c1*2+1];
    const float wl00 = wlv[c0*2+0], wl01 = wlv[c0*2+1];
    const float wl10 = wlv[c1*2+0], wl11 = wlv[c1*2+1];
    float pr[4][4];
    #pragma unroll
    for (int r = 0; r < 4; ++r) {
        const float h0 = fmaxf(acc0[r] + b0v, 0.0f);
        const float h1 = fmaxf(acc1[r] + b1v, 0.0f);
        pr[r][0] = fmaf(h0, wm00, h1*wm10);
        pr[r][1] = fmaf(h0, wm01, h1*wm11);
        pr[r][2] = fmaf(h0, wl00, h1*wl10);
        pr[r][3] = fmaf(h0, wl01, h1*wl11);
    }
    #pragma unroll
    for (int m = 1; m <= 8; m <<= 1)
        #pragma unroll
        for (int r = 0; r < 4; ++r)
            #pragma unroll
            for (int j = 0; j < 4; ++j)
                pr[r][j] += __shfl_xor(pr[r][j], m);
    if (ln == 0) {
        const int part = blockIdx.x*2 + (wv & 1);
        #pragma unroll
        for (int r = 0; r < 4; ++r) {
            const int row = row0 + wm + q*4 + r;
            *(float4*)&pmulv[(size_t)row*128 + part*4] =
                make_float4(pr[r][0], pr[r][1], pr[r][2], pr[r][3]);
        }
    }
}

// ---------------------------------------------------------------------------
// gemm3: decoder layer 1. Pre-phase: 256 threads reduce pmulv (8 thr/row)
// -> z in LDS; staging patch injects z into cols 0..1.
// ---------------------------------------------------------------------------
__global__ __launch_bounds__(256) void gemm_zfix(
    const __bf16* __restrict__ A, const __bf16* __restrict__ Wt,
    const float* __restrict__ bias, __bf16* __restrict__ C, int Kp,
    const float* __restrict__ pmulv, const float* __restrict__ bmu,
    const float* __restrict__ blv, const float* __restrict__ eps)
{
    __shared__ float zsh[32][2];
    const int tid = threadIdx.x;
    {
        const int row = tid >> 3, pg = tid & 7;      // 8 threads per row
        const int ra = blockIdx.y*32 + row;
        float4 s = make_float4(0.0f, 0.0f, 0.0f, 0.0f);
        #pragma unroll
        for (int p = pg*4; p < pg*4 + 4; ++p) {
            const float4 qa = *(const float4*)&pmulv[(size_t)ra*128 + p*4];
            s.x += qa.x; s.y += qa.y; s.z += qa.z; s.w += qa.w;
        }
        #pragma unroll
        for (int m = 1; m <= 4; m <<= 1) {
            s.x += __shfl_down(s.x, m);
            s.y += __shfl_down(s.y, m);
            s.z += __shfl_down(s.z, m);
            s.w += __shfl_down(s.w, m);
        }
        if (pg == 0) {
            zsh[row][0] = fmaf(expf(0.5f*(s.z + blv[0])), eps[ra*2+0], s.x + bmu[0]);
            zsh[row][1] = fmaf(expf(0.5f*(s.w + blv[1])), eps[ra*2+1], s.y + bmu[1]);
        }
    }
    __syncthreads();
    GEMM_CORE(A, Wt, Kp,
        if (ch == 0) {
            va[0] = (__bf16)zsh[r16][0];
            va[1] = (__bf16)zsh[r16][1];
            vb[0] = (__bf16)zsh[r16 + 16][0];
            vb[1] = (__bf16)zsh[r16 + 16][1];
        }
    )
    GEMM_WRITE_RELU(C)
}

// ---------------------------------------------------------------------------
// gemm4: decoder layer 2 + fused nn_out PARTIAL dots -> pnn[row][32][8].
// ---------------------------------------------------------------------------
__global__ __launch_bounds__(256) void gemm_out8(
    const __bf16* __restrict__ A, const __bf16* __restrict__ Wt,
    const float* __restrict__ bias, const float* __restrict__ w3,
    float* __restrict__ pnn, int Kp)
{
    const int tid = threadIdx.x;
    GEMM_CORE(A, Wt, Kp)
    const int c0 = col0 + wn + ln;
    const int c1 = c0 + 16;
    const float b0v = bias[c0], b1v = bias[c1];
    float pr[4][8];
    #pragma unroll
    for (int r = 0; r < 4; ++r) {
        const float h0 = fmaxf(acc0[r] + b0v, 0.0f);
        const float h1 = fmaxf(acc1[r] + b1v, 0.0f);
        #pragma unroll
        for (int j = 0; j < 8; ++j)
            pr[r][j] = fmaf(h0, w3[c0*8 + j], h1*w3[c1*8 + j]);
    }
    #pragma unroll
    for (int m = 1; m <= 8; m <<= 1)
        #pragma unroll
        for (int r = 0; r < 4; ++r)
            #pragma unroll
            for (int j = 0; j < 8; ++j)
                pr[r][j] += __shfl_xor(pr[r][j], m);
    if (ln == 0) {
        const int part = blockIdx.x*2 + (wv & 1);
        #pragma unroll
        for (int r = 0; r < 4; ++r) {
            const int row = row0 + wm + q*4 + r;
            *(float4*)&pnn[(size_t)row*256 + part*8] =
                make_float4(pr[r][0], pr[r][1], pr[r][2], pr[r][3]);
            *(float4*)&pnn[(size_t)row*256 + part*8 + 4] =
                make_float4(pr[r][4], pr[r][5], pr[r][6], pr[r][7]);
        }
    }
}

// ---------------------------------------------------------------------------
// ADMM solver — 512 threads (8 waves): waves 0-3 = R16 phase A/C verbatim;
// waves 4-7 = phase B as 231 THIRD-dots (9 b128/lane, was 13). Grid 1024 ->
// 4 blocks/CU x 8 waves = 32 waves/CU (hardware max; VGPR 64 budget).
// ---------------------------------------------------------------------------
#define DOT11(bb, a0, a1, a2) \
    fmaf(bb[0],a0.x, fmaf(bb[1],a0.y, fmaf(bb[2],a0.z, fmaf(bb[3],a0.w, \
    fmaf(bb[4],a1.x, fmaf(bb[5],a1.y, fmaf(bb[6],a1.z, fmaf(bb[7],a1.w, \
    fmaf(bb[8],a2.x, fmaf(bb[9],a2.y, bb[10]*a2.z))))))))))

__global__ __launch_bounds__(512) void solver_kernel(
    const float* __restrict__ pnn, const float* __restrict__ b3,
    const float* __restrict__ inp,
    const float* __restrict__ ise, const float* __restrict__ yub_p,
    const float* __restrict__ ylb_p,
    const float* __restrict__ Pg, const float* __restrict__ Pdg,
    const float* __restrict__ Pddg,
    const float* __restrict__ ws, float* __restrict__ out)
{
    __shared__ __align__(16) float sBcol[3][11][108];
    __shared__ float s_i2x[196], s_i2y[225], sR2x[121], sR2y[121];
    __shared__ __align__(16) float rows[7][108];
    __shared__ float dval[3][80];
    __shared__ __align__(16) float cxs[12], cys[12];
    __shared__ float wlin[24];
    __shared__ float obsS[4][10];
    __shared__ float nnS[8];

    const int tid = threadIdx.x;
    const int e = blockIdx.x;

    for (int i = tid; i < 3*11*108; i += 512) {
        const int mat = i / 1188, rem = i - mat*1188;
        const int k = rem / 108, t = rem - k*108;
        const float* G = (mat == 0) ? Pg : (mat == 1 ? Pdg : Pddg);
        sBcol[mat][k][t] = (t < NUMPT) ? G[t*NVAR + k] : 0.0f;
    }
    for (int i = tid; i < 196; i += 512) s_i2x[i] = ws[WS_INV2X + i];
    for (int i = tid; i < 225; i += 512) s_i2y[i] = ws[WS_INV2Y + i];
    for (int i = tid; i < 121; i += 512) { sR2x[i] = ws[WS_R2X + i]; sR2y[i] = ws[WS_R2Y + i]; }
    if (tid >= 112 && tid < 152) {
        const int i = tid - 112;
        obsS[i/10][i%10] = inp[e*INPD + 5 + (i/10) + 5*(i%10)];
    }
    if (tid >= 192 && tid < 256) {   // nn_out = b3 + 32 partials (parallel tree)
        const int l = tid - 192;
        const int j = l & 7, pg = l >> 3;
        float s = 0.0f;
        #pragma unroll
        for (int p = pg*4; p < pg*4 + 4; ++p)
            s += pnn[(size_t)e*256 + p*8 + j];
        s += __shfl_down(s, 8);
        s += __shfl_down(s, 16);
        s += __shfl_down(s, 32);
        if (pg == 0) nnS[j] = b3[j] + s;
    }
    if (tid >= 296 && tid < 352) {   // zero 7 rows x 8 tail pads (wave 4)
        const int i = tid - 296;
        rows[i >> 3][100 + (i & 7)] = 0.0f;
    }
    if (tid == 92) cxs[11] = 0.0f;
    if (tid == 93) cys[11] = 0.0f;

    // ---- roles ----
    const bool isA = (tid < 200);               // waves 0..3
    const int tA = tid >> 1, hA2 = tid & 1;
    const bool isB = (tid >= 256 && tid < 487); // waves 4..7: 231 third-dots
    const int bI = tid - 256;
    const int hB = bI / 77;                     // third index 0..2
    const int dB = bI - 77*hB;
    const int rB = dB / 11, kB = dB - 11*rB;
    const int mB = (rB==1||rB==4) ? 2 : ((rB==2||rB==5) ? 1 : 0);
    const float* colp = &sBcol[mB][kB][hB*36];
    const float* rowp = &rows[rB][hB*36];

    float bP[NVAR], bQ[NVAR];
    if (isA) {
        const float* Qsrc = hA2 ? Pddg : Pdg;
        #pragma unroll
        for (int k = 0; k < NVAR; ++k) {
            bP[k] = Pg[tA*NVAR+k];
            bQ[k] = Qsrc[tA*NVAR+k];
        }
    }

    const float vx0 = ise[e*4 + 2], vy0 = ise[e*4 + 3];
    const float yub = yub_p[e], ylb = ylb_p[e];
    __syncthreads();

    const float DT = T_FIN_C / 99.0f;
    float xo[5], yo[5];
    if (isA) {
        const int ob0 = 5*hA2;
        #pragma unroll
        for (int o = 0; o < 5; ++o) {
            xo[o] = fmaf(obsS[2][ob0+o], tA*DT, obsS[0][ob0+o]);
            yo[o] = fmaf(obsS[3][ob0+o], tA*DT, obsS[1][ob0+o]);
        }
    }

    if (tid < 11) {
        float s = 0;
        #pragma unroll
        for (int c = 0; c < 4; ++c)
            s = fmaf(nnS[c], ws[WS_SVD + c*11 + tid], s);
        wlin[tid] = RHO_V_C * K_P_V_C * s;
    } else if (tid < 22) {
        const int k = tid - 11;
        float s = 0;
        #pragma unroll
        for (int c = 0; c < 4; ++c)
            s = fmaf(nnS[4 + c], ws[WS_SPD + c*11 + k], s);
        wlin[tid] = RHO_OFFSET_C * K_P_C * s;
    }
    __syncthreads();

    float lam = 0.0f, cb = 0.0f;
    if (tid < 11) {
        const int k = tid;
        float a = vx0 * ws[WS_INV1X + k*14 + 12];
        #pragma unroll
        for (int j = 0; j < NVAR; ++j)
            a = fmaf(-wlin[j], ws[WS_INV1X + k*14 + j], a);
        cb = a; cxs[k] = a;
    } else if (tid < 22) {
        const int k = tid - 11;
        float a = vy0 * ws[WS_INV1Y + k*15 + 12];
        #pragma unroll
        for (int j = 0; j < NVAR; ++j)
            a = fmaf(-wlin[11 + j], ws[WS_INV1Y + k*15 + j], a);
        cb = a; cys[k] = a;
    }
    __syncthreads();

    for (int it = 0; it < MAXIT; ++it) {
        // -------- phase A (waves 0-3) --------
        if (isA) {
            const float4 x0 = *(const float4*)&cxs[0];
            const float4 x1 = *(const float4*)&cxs[4];
            const float4 x2 = *(const float4*)&cxs[8];
            const float4 y0 = *(const float4*)&cys[0];
            const float4 y1 = *(const float4*)&cys[4];
            const float4 y2 = *(const float4*)&cys[8];
            const float px = DOT11(bP, x0, x1, x2);
            const float py = DOT11(bP, y0, y1, y2);
            const float qx = DOT11(bQ, x0, x1, x2);
            const float qy = DOT11(bQ, y0, y1, y2);

            float srx = 0.0f, sry = 0.0f;
            #pragma unroll
            for (int o = 0; o < 5; ++o) {
                const float wc = px - xo[o], wsv = py - yo[o];
                const float aw = A_OBS_C * wsv, bw = B_OBS_C * wc;
                const float r2 = aw*aw + bw*bw;
                if (r2 > 0.0f) {
                    const float f = (r2 < ABSQ_C) ? (1.0f - AB_C * rsqrtf(r2)) : 0.0f;
                    srx = fmaf(wc, f, srx);
                    sry = fmaf(wsv, f, sry);
                } else {
                    srx -= A_OBS_C;
                }
            }
            const float mrx = srx + __shfl_xor(srx, 1);
            const float mry = sry + __shfl_xor(sry, 1);

            if (hA2 == 0) {
                rows[0][tA] = mrx;
                rows[3][tA] = mry;
                const float rv2 = qx*qx + qy*qy;
                float vxr, vyr;
                if (rv2 > 0.0f) {
                    const float ri = rsqrtf(rv2);
                    const float dv = fminf(fmaxf(rv2*ri, V_MIN_C), V_MAX_C);
                    const float f = 1.0f - dv*ri;
                    vxr = qx*f; vyr = qy*f;
                } else { vxr = -V_MIN_C; vyr = 0.0f; }
                rows[2][tA] = vxr;  rows[5][tA] = vyr;
                rows[6][tA] = fmaxf(0.0f, py - yub) - fmaxf(0.0f, ylb - py);
            } else {
                const float ra2 = qx*qx + qy*qy;
                float axr = 0.0f, ayr = 0.0f;
                if (ra2 > A_MAX_C*A_MAX_C) {
                    const float ri = rsqrtf(ra2);
                    const float f = 1.0f - A_MAX_C*ri;
                    axr = qx*f; ayr = qy*f;
                }
                rows[1][tA] = axr;  rows[4][tA] = ayr;
            }
        }
        __syncthreads();

        // -------- phase B (waves 4-7): 231 third-dots, 9 b128 each --------
        if (isB) {
            float s0 = 0.0f, s1 = 0.0f;
            #pragma unroll
            for (int i = 0; i < 9; ++i) {
                const float4 rr = *(const float4*)&rowp[i*4];
                const float4 cc = *(const float4*)&colp[i*4];
                s0 = fmaf(rr.x, cc.x, s0); s1 = fmaf(rr.y, cc.y, s1);
                s0 = fmaf(rr.z, cc.z, s0); s1 = fmaf(rr.w, cc.w, s1);
            }
            dval[hB][dB] = s0 + s1;
        }
        __syncthreads();

        // -------- phase C (wave 0, lanes 0..21) --------
        if (tid < 22) {
            const int k = (tid < 11) ? tid : tid - 11;
            float u;
            if (tid < 11)
                u = RHO_OBS_C * ((dval[0][k]      + dval[1][k]      + dval[2][k])
                               + (dval[0][11 + k] + dval[1][11 + k] + dval[2][11 + k])
                               + (dval[0][22 + k] + dval[1][22 + k] + dval[2][22 + k]));
            else
                u = RHO_OBS_C * ((dval[0][33 + k] + dval[1][33 + k] + dval[2][33 + k])
                               + (dval[0][44 + k] + dval[1][44 + k] + dval[2][44 + k])
                               + (dval[0][55 + k] + dval[1][55 + k] + dval[2][55 + k])
                               + (dval[0][66 + k] + dval[1][66 + k] + dval[2][66 + k]));
            wlin[tid] = 2.0f*u - lam - cb;
            lam -= u;
        }
        __builtin_amdgcn_wave_barrier();
        if (tid < 22) {
            const int k = (tid < 11) ? tid : tid - 11;
            if (tid < 11) {
                float a = vx0 * s_i2x[k*14 + 12];
                #pragma unroll
                for (int j = 0; j < NVAR; ++j) {
                    a = fmaf(-wlin[j], s_i2x[k*14 + j], a);
                    a = fmaf(sR2x[k*11 + j], cxs[j], a);
                }
                cxs[k] = a;
            } else {
                float a = vy0 * s_i2y[k*15 + 12];
                #pragma unroll
                for (int j = 0; j < NVAR; ++j) {
                    a = fmaf(-wlin[11 + j], s_i2y[k*15 + j], a);
                    a = fmaf(sR2y[k*11 + j], cys[j], a);
                }
                cys[k] = a;
            }
        }
        __syncthreads();
    }

    if (tid < NVAR) {
        out[e*22 + tid]      = cxs[tid];
        out[e*22 + 11 + tid] = cys[tid];
    }
}

// ---------------------------------------------------------------------------
extern "C" void kernel_launch(void* const* d_in, const int* in_sizes, int n_in,
                              void* d_out, int out_size, void* d_ws, size_t ws_size,
                              hipStream_t stream)
{
    (void)in_sizes; (void)n_in; (void)out_size; (void)ws_size;
    const float* inp    = (const float*)d_in[0];
    const float* ise    = (const float*)d_in[1];
    const float* traj   = (const float*)d_in[2];
    const float* yub    = (const float*)d_in[3];
    const float* ylb    = (const float*)d_in[4];
    const float* eps    = (const float*)d_in[5];
    const float* enc_w1 = (const float*)d_in[6];
    const float* enc_b1 = (const float*)d_in[7];
    const float* enc_w2 = (const float*)d_in[8];
    const float* enc_b2 = (const float*)d_in[9];
    const float* wmu    = (const float*)d_in[10];
    const float* bmu    = (const float*)d_in[11];
    const float* wlv    = (const float*)d_in[12];
    const float* blv    = (const float*)d_in[13];
    const float* dec_w1 = (const float*)d_in[14];
    const float* dec_b1 = (const float*)d_in[15];
    const float* dec_w2 = (const float*)d_in[16];
    const float* dec_b2 = (const float*)d_in[17];
    const float* dec_w3 = (const float*)d_in[18];
    const float* dec_b3 = (const float*)d_in[19];
    const float* P      = (const float*)d_in[20];
    const float* Pd     = (const float*)d_in[21];
    const float* Pdd    = (const float*)d_in[22];
    const float* mean   = (const float*)d_in[23];
    const float* stdv   = (const float*)d_in[24];

    float* ws    = (float*)d_ws;
    float* pmulv = ws + WS_BIG;                       // 1024 x 32 x 4
    float* pnn   = pmulv + (size_t)BATCH*128;         // 1024 x 32 x 8
    __bf16* bfb  = (__bf16*)(pnn + (size_t)BATCH*256);
    __bf16* enc_in = bfb;                             // 1024 x 256
    __bf16* dec_in = enc_in + (size_t)BATCH*256;      // 1024 x 128
    __bf16* hA     = dec_in + (size_t)BATCH*128;      // 1024 x 1024
    __bf16* wt1    = hA + (size_t)BATCH*HID;          // 1024 x 256
    __bf16* wt2    = wt1 + (size_t)HID*256;           // 1024 x 1024
    __bf16* wt3    = wt2 + (size_t)HID*HID;           // 1024 x 128
    __bf16* wt4    = wt3 + (size_t)HID*128;           // 1024 x 1024
    float* outf = (float*)d_out;

    setup_kernel<<<4 + 1024 + 608, 256, 0, stream>>>(
        P, Pd, Pdd, ws, inp, traj, mean, stdv, enc_in, dec_in,
        enc_w1, enc_w2, dec_w1, dec_w2, wt1, wt2, wt3, wt4);

    dim3 g(16, 32);   // 32x64 tiles -> 512 blocks -> 2 blocks/CU (best)
    gemm_relu<<<g, 256, 0, stream>>>(enc_in, wt1, enc_b1, hA, 256);
    gemm_mulv<<<g, 256, 0, stream>>>(hA, wt2, enc_b2, wmu, wlv, pmulv, 1024);
    gemm_zfix<<<g, 256, 0, stream>>>(dec_in, wt3, dec_b1, hA, 128,
                                     pmulv, bmu, blv, eps);
    gemm_out8<<<g, 256, 0, stream>>>(hA, wt4, dec_b2, dec_w3, pnn, 1024);
    solver_kernel<<<BATCH, 512, 0, stream>>>(pnn, dec_b3, inp, ise, yub, ylb,
                                             P, Pd, Pdd, ws, outf);
}

// Round 21
// 212.337 us; speedup vs baseline: 1.1288x; 1.1288x over previous
//
#include <hip/hip_runtime.h>
#include <hip/hip_bf16.h>
#include <math.h>

// ---------------- problem constants ----------------
#define BATCH   1024
#define NUMPT   100
#define NVAR    11
#define NOBS    10
#define HID     1024
#define INPD    55
#define TRAJD   200

#define T_FIN_C   15.0f
#define K_P_C     20.0f
#define K_D_C     8.944271909999159f   // 2*sqrt(20)
#define K_P_V_C   20.0f
#define A_OBS_C   8.0f
#define B_OBS_C   4.2f
#define AB_C      33.6f                 // A_OBS*B_OBS
#define ABSQ_C    1128.96f              // (A_OBS*B_OBS)^2
#define RHO_V_C      1.0f
#define RHO_PROJ_C   1.0f
#define RHO_LANE_C   100.0f
#define RHO_OBS_C    100.0f
#define RHO_OFFSET_C 1.0f
#define RHO_INEQ_C   100.0f
#define V_MIN_C   0.1f
#define V_MAX_C   30.0f
#define A_MAX_C   8.0f
#define MAXIT     20

// workspace layout (float offsets)
#define WS_INV1X  0      // 14x14
#define WS_INV1Y  256    // 15x15
#define WS_INV2X  512    // 14x14
#define WS_INV2Y  768    // 15x15
#define WS_SVD    1024   // 4x11 chunk-summed A_vd
#define WS_SPD    1088   // 4x11 chunk-summed A_pd
#define WS_QX     1152   // 11x11
#define WS_QY     1280   // 11x11
#define WS_R2X    1408   // 11x11  inv2x[:11,:11] @ Qx
#define WS_R2Y    1536   // 11x11
#define WS_BIG    2048

typedef __bf16 bf16x8 __attribute__((ext_vector_type(8)));
typedef float  f32x4  __attribute__((ext_vector_type(4)));

// ---------------------------------------------------------------------------
// Fused setup kernel (grid 4 + 1024 + 608) — R13/R16 verbatim (4-block GJ:
// block-parallel across 4 CUs).
// ---------------------------------------------------------------------------
__global__ __launch_bounds__(256) void setup_kernel(
    const float* __restrict__ Pg, const float* __restrict__ Pdg,
    const float* __restrict__ Pddg, float* __restrict__ ws,
    const float* __restrict__ inp, const float* __restrict__ traj,
    const float* __restrict__ mean, const float* __restrict__ stdv,
    __bf16* __restrict__ enc_in, __bf16* __restrict__ dec_in,
    const float* __restrict__ w1, const float* __restrict__ w2,
    const float* __restrict__ w3, const float* __restrict__ w4,
    __bf16* __restrict__ o1, __bf16* __restrict__ o2,
    __bf16* __restrict__ o3, __bf16* __restrict__ o4)
{
    __shared__ float sP[NUMPT*NVAR], sPd[NUMPT*NVAR], sPdd[NUMPT*NVAR];
    __shared__ float aug[15][31];
    __shared__ float fcol[15];
    __shared__ float sQ[121];
    __shared__ float sn[INPD];
    __shared__ float tile[64][65];
    __shared__ float s_pivinv;
    __shared__ int   s_pidx;
    const int tid = threadIdx.x, bid = blockIdx.x;

    if (bid >= 1028) {   // ------------- tiled weight transpose -------------
        const int tb = bid - 1028;
        int wsel, kt, nt;
        if (tb < 64)       { wsel = 0; kt = tb >> 4;        nt = tb & 15; }
        else if (tb < 320) { wsel = 1; kt = (tb-64) >> 4;   nt = (tb-64) & 15; }
        else if (tb < 352) { wsel = 2; kt = (tb-320) >> 4;  nt = (tb-320) & 15; }
        else               { wsel = 3; kt = (tb-352) >> 4;  nt = (tb-352) & 15; }
        const float* W = (wsel==0) ? w1 : (wsel==1) ? w2 : (wsel==2) ? w3 : w4;
        __bf16* O      = (wsel==0) ? o1 : (wsel==1) ? o2 : (wsel==2) ? o3 : o4;
        const int K  = (wsel==0) ? 255 : (wsel==2) ? 57 : 1024;
        const int Kp = (wsel==0) ? 256 : (wsel==2) ? 128 : 1024;
        if (kt*64 >= Kp) return;
        const int k0 = kt*64, n0 = nt*64;
        const int rr = tid >> 6, c = tid & 63;
        #pragma unroll 4
        for (int it = 0; it < 16; ++it) {
            const int r = it*4 + rr;
            tile[r][c] = (k0 + r < K) ? W[(size_t)(k0 + r)*HID + n0 + c] : 0.0f;
        }
        __syncthreads();
        #pragma unroll 4
        for (int it = 0; it < 16; ++it) {
            const int r = it*4 + rr;
            O[(size_t)(n0 + r)*Kp + k0 + c] = (__bf16)tile[c][r];
        }
        return;
    }

    if (bid >= 4) {      // ---------------- input prep ----------------
        const int b = bid - 4;
        if (tid < INPD) {
            const float v = (inp[b*INPD + tid] - mean[tid]) / stdv[tid];
            sn[tid] = v;
            enc_in[b*256 + tid] = (__bf16)v;
        } else if (tid < 255) {
            enc_in[b*256 + tid] = (__bf16)traj[b*TRAJD + (tid - INPD)];
        } else {
            enc_in[b*256 + 255] = (__bf16)0.0f;
        }
        __syncthreads();
        if (tid >= 2 && tid < 128)
            dec_in[b*128 + tid] = (__bf16)((tid < 57) ? sn[tid - 2] : 0.0f);
        return;
    }

    // ---------------- precompute (bid 0..3) ----------------
    for (int i = tid; i < NUMPT*NVAR; i += 256) {
        sP[i] = Pg[i]; sPd[i] = Pdg[i]; sPdd[i] = Pddg[i];
    }
    for (int i = tid; i < 15*31; i += 256) (&aug[0][0])[i] = 0.0f;
    __syncthreads();

    const int N = (bid == 0 || bid == 2) ? 14 : 15;

    if (tid < 121) {
        const int i = tid / 11, j = tid % 11;
        float s = 0.0f;
        if (bid == 0) {
            for (int t = 0; t < NUMPT; ++t) {
                float pdd_i = sPdd[t*NVAR+i], pdd_j = sPdd[t*NVAR+j];
                float av_i = pdd_i - K_P_V_C * sPd[t*NVAR+i];
                float av_j = pdd_j - K_P_V_C * sPd[t*NVAR+j];
                s += pdd_i*pdd_j + RHO_V_C * av_i*av_j;
            }
        } else if (bid == 1) {
            for (int t = 0; t < NUMPT; ++t) {
                float pdd_i = sPdd[t*NVAR+i], pdd_j = sPdd[t*NVAR+j];
                float ap_i = pdd_i - K_P_C*sP[t*NVAR+i] - K_D_C*sPd[t*NVAR+i];
                float ap_j = pdd_j - K_P_C*sP[t*NVAR+j] - K_D_C*sPd[t*NVAR+j];
                s += pdd_i*pdd_j + RHO_OFFSET_C * ap_i*ap_j;
            }
        } else {
            float obs_w = RHO_OBS_C * (float)NOBS;
            if (bid == 3) obs_w += RHO_LANE_C * 2.0f;
            for (int t = 0; t < NUMPT; ++t) {
                float p_i = sP[t*NVAR+i],   p_j = sP[t*NVAR+j];
                float pd_i = sPd[t*NVAR+i], pd_j = sPd[t*NVAR+j];
                float pdd_i = sPdd[t*NVAR+i], pdd_j = sPdd[t*NVAR+j];
                s += obs_w*p_i*p_j + RHO_INEQ_C*(pdd_i*pdd_j + pd_i*pd_j);
            }
            if (i == j) s += RHO_PROJ_C;
        }
        aug[i][j] = s;
    }
    if (tid < 11) {
        const int i = tid;
        float a0 = sP[i], a1 = sPd[i], a2 = sPdd[i];
        aug[i][11] = a0; aug[11][i] = a0;
        aug[i][12] = a1; aug[12][i] = a1;
        aug[i][13] = a2; aug[13][i] = a2;
        if (N == 15) { float a3 = sPd[99*NVAR + i]; aug[i][14] = a3; aug[14][i] = a3; }
    }
    if (tid < N) aug[tid][N + tid] = 1.0f;

    if (bid == 0 && tid < 44) {
        const int c = tid / 11, k = tid % 11;
        float sv = 0.0f, sp = 0.0f;
        for (int t = 25*c; t < 25*c + 25; ++t) {
            float p = sP[t*NVAR+k], pd = sPd[t*NVAR+k], pdd = sPdd[t*NVAR+k];
            sv += pdd - K_P_V_C * pd;
            sp += pdd - K_P_C * p - K_D_C * pd;
        }
        ws[WS_SVD + tid] = sv;
        ws[WS_SPD + tid] = sp;
    }
    __syncthreads();

    if ((bid == 2 || bid == 3) && tid < 121) {
        float v = aug[tid/11][tid%11];
        if (tid/11 == tid%11) v -= RHO_PROJ_C;
        sQ[tid] = v;
        ws[(bid == 2 ? WS_QX : WS_QY) + tid] = v;
    }

    for (int k = 0; k < N; ++k) {
        if (tid == 0) {
            int p = k; float best = fabsf(aug[k][k]);
            for (int i = k+1; i < N; ++i) {
                float v = fabsf(aug[i][k]);
                if (v > best) { best = v; p = i; }
            }
            s_pidx = p;
        }
        __syncthreads();
        const int p = s_pidx;
        if (p != k && tid < 2*N) {
            float tmp = aug[k][tid]; aug[k][tid] = aug[p][tid]; aug[p][tid] = tmp;
        }
        __syncthreads();
        if (tid == 0) s_pivinv = 1.0f / aug[k][k];
        __syncthreads();
        if (tid < 2*N) aug[k][tid] *= s_pivinv;
        __syncthreads();
        if (tid < N) fcol[tid] = (tid == k) ? 0.0f : aug[tid][k];
        __syncthreads();
        for (int idx = tid; idx < N*2*N; idx += 256) {
            const int i = idx / (2*N), j = idx % (2*N);
            if (i != k) aug[i][j] = fmaf(-fcol[i], aug[k][j], aug[i][j]);
        }
        __syncthreads();
    }

    float* dst = ws + (bid == 0 ? WS_INV1X : bid == 1 ? WS_INV1Y
                      : bid == 2 ? WS_INV2X : WS_INV2Y);
    for (int idx = tid; idx < N*N; idx += 256)
        dst[idx] = aug[idx / N][N + idx % N];
    __syncthreads();

    if ((bid == 2 || bid == 3) && tid < 121) {
        const int k = tid / 11, j = tid % 11;
        float a = 0.0f;
        #pragma unroll
        for (int m = 0; m < 11; ++m) a = fmaf(aug[k][N + m], sQ[m*11 + j], a);
        ws[(bid == 2 ? WS_R2X : WS_R2Y) + tid] = a;
    }
}

// ---------------------------------------------------------------------------
// Shared GEMM core, double-buffered LDS (R16 measured-best). 32x64 tile,
// BK=128, 4 waves. Grid (16,32) = 512 blocks -> 2 blocks/CU.
// __VA_ARGS__ = optional staging patch (k0 = 0 prologue only).
// ---------------------------------------------------------------------------
#define GEMM_CORE(A_, Wt_, Kp_, ...)                                          \
    __shared__ __bf16 As[2][32][136];                                         \
    __shared__ __bf16 Bs[2][64][136];                                         \
    const int lane = tid & 63, wv = tid >> 6;                                 \
    const int wm = (wv >> 1) * 16, wn = (wv & 1) * 32;                        \
    const int ln = lane & 15, q = lane >> 4;                                  \
    const int row0 = blockIdx.y * 32, col0 = blockIdx.x * 64;                 \
    const int r16 = tid >> 4, ch = (tid & 15) * 8;                            \
    f32x4 acc0 = (f32x4){0,0,0,0}, acc1 = (f32x4){0,0,0,0};                   \
    {                                                                         \
        bf16x8 va = *(const bf16x8*)&(A_)[(size_t)(row0 + r16)*(Kp_) + ch];   \
        bf16x8 vb = *(const bf16x8*)&(A_)[(size_t)(row0 + r16 + 16)*(Kp_) + ch]; \
        __VA_ARGS__                                                           \
        *(bf16x8*)&As[0][r16][ch] = va;                                       \
        *(bf16x8*)&As[0][r16 + 16][ch] = vb;                                  \
        _Pragma("unroll")                                                     \
        for (int p = 0; p < 4; ++p)                                           \
            *(bf16x8*)&Bs[0][r16 + 16*p][ch] =                                \
                *(const bf16x8*)&(Wt_)[(size_t)(col0 + r16 + 16*p)*(Kp_) + ch]; \
    }                                                                         \
    __syncthreads();                                                          \
    int cur = 0;                                                              \
    for (int k0 = 128; k0 < (Kp_); k0 += 128) {                               \
        const bf16x8 nva = *(const bf16x8*)&(A_)[(size_t)(row0 + r16)*(Kp_) + k0 + ch]; \
        const bf16x8 nvb = *(const bf16x8*)&(A_)[(size_t)(row0 + r16 + 16)*(Kp_) + k0 + ch]; \
        const bf16x8 nw0 = *(const bf16x8*)&(Wt_)[(size_t)(col0 + r16)*(Kp_) + k0 + ch]; \
        const bf16x8 nw1 = *(const bf16x8*)&(Wt_)[(size_t)(col0 + r16 + 16)*(Kp_) + k0 + ch]; \
        const bf16x8 nw2 = *(const bf16x8*)&(Wt_)[(size_t)(col0 + r16 + 32)*(Kp_) + k0 + ch]; \
        const bf16x8 nw3 = *(const bf16x8*)&(Wt_)[(size_t)(col0 + r16 + 48)*(Kp_) + k0 + ch]; \
        _Pragma("unroll")                                                     \
        for (int kc = 0; kc < 4; ++kc) {                                      \
            const bf16x8 a  = *(const bf16x8*)&As[cur][wm + ln][kc*32 + q*8]; \
            const bf16x8 b0 = *(const bf16x8*)&Bs[cur][wn + ln][kc*32 + q*8]; \
            const bf16x8 b1 = *(const bf16x8*)&Bs[cur][wn + 16 + ln][kc*32 + q*8]; \
            acc0 = __builtin_amdgcn_mfma_f32_16x16x32_bf16(a, b0, acc0, 0, 0, 0); \
            acc1 = __builtin_amdgcn_mfma_f32_16x16x32_bf16(a, b1, acc1, 0, 0, 0); \
        }                                                                     \
        const int nxt = cur ^ 1;                                              \
        *(bf16x8*)&As[nxt][r16][ch] = nva;                                    \
        *(bf16x8*)&As[nxt][r16 + 16][ch] = nvb;                               \
        *(bf16x8*)&Bs[nxt][r16][ch] = nw0;                                    \
        *(bf16x8*)&Bs[nxt][r16 + 16][ch] = nw1;                               \
        *(bf16x8*)&Bs[nxt][r16 + 32][ch] = nw2;                               \
        *(bf16x8*)&Bs[nxt][r16 + 48][ch] = nw3;                               \
        __syncthreads();                                                      \
        cur = nxt;                                                            \
    }                                                                         \
    _Pragma("unroll")                                                         \
    for (int kc = 0; kc < 4; ++kc) {                                          \
        const bf16x8 a  = *(const bf16x8*)&As[cur][wm + ln][kc*32 + q*8];     \
        const bf16x8 b0 = *(const bf16x8*)&Bs[cur][wn + ln][kc*32 + q*8];     \
        const bf16x8 b1 = *(const bf16x8*)&Bs[cur][wn + 16 + ln][kc*32 + q*8]; \
        acc0 = __builtin_amdgcn_mfma_f32_16x16x32_bf16(a, b0, acc0, 0, 0, 0); \
        acc1 = __builtin_amdgcn_mfma_f32_16x16x32_bf16(a, b1, acc1, 0, 0, 0); \
    }

#define GEMM_WRITE_RELU(C_)                                                   \
    _Pragma("unroll")                                                         \
    for (int ni = 0; ni < 2; ++ni) {                                          \
        const int col = col0 + wn + ni*16 + ln;                               \
        const float bv = bias[col];                                           \
        const f32x4 av = ni ? acc1 : acc0;                                    \
        _Pragma("unroll")                                                     \
        for (int r = 0; r < 4; ++r) {                                         \
            const int row = row0 + wm + q*4 + r;                              \
            (C_)[(size_t)row * HID + col] = (__bf16)fmaxf(av[r] + bv, 0.0f);  \
        }                                                                     \
    }

// ---------------------------------------------------------------------------
__global__ __launch_bounds__(256) void gemm_relu(
    const __bf16* __restrict__ A, const __bf16* __restrict__ Wt,
    const float* __restrict__ bias, __bf16* __restrict__ C, int Kp)
{
    const int tid = threadIdx.x;
    GEMM_CORE(A, Wt, Kp)
    GEMM_WRITE_RELU(C)
}

// ---------------------------------------------------------------------------
// gemm2: encoder layer 2 + fused mu/logvar PARTIAL dots -> pmulv[row][32][4].
// ---------------------------------------------------------------------------
__global__ __launch_bounds__(256) void gemm_mulv(
    const __bf16* __restrict__ A, const __bf16* __restrict__ Wt,
    const float* __restrict__ bias,
    const float* __restrict__ wmu, const float* __restrict__ wlv,
    float* __restrict__ pmulv, int Kp)
{
    const int tid = threadIdx.x;
    GEMM_CORE(A, Wt, Kp)
    const int c0 = col0 + wn + ln;
    const int c1 = c0 + 16;
    const float b0v = bias[c0], b1v = bias[c1];
    const float wm00 = wmu[c0*2+0], wm01 = wmu[c0*2+1];
    const float wm10 = wmu[c1*2+0], wm11 = wmu[c1*2+1];
    const float wl00 = wlv[c0*2+0], wl01 = wlv[c0*2+1];
    const float wl10 = wlv[c1*2+0], wl11 = wlv[c1*2+1];
    float pr[4][4];
    #pragma unroll
    for (int r = 0; r < 4; ++r) {
        const float h0 = fmaxf(acc0[r] + b0v, 0.0f);
        const float h1 = fmaxf(acc1[r] + b1v, 0.0f);
        pr[r][0] = fmaf(h0, wm00, h1*wm10);
        pr[r][1] = fmaf(h0, wm01, h1*wm11);
        pr[r][2] = fmaf(h0, wl00, h1*wl10);
        pr[r][3] = fmaf(h0, wl01, h1*wl11);
    }
    #pragma unroll
    for (int m = 1; m <= 8; m <<= 1)
        #pragma unroll
        for (int r = 0; r < 4; ++r)
            #pragma unroll
            for (int j = 0; j < 4; ++j)
                pr[r][j] += __shfl_xor(pr[r][j], m);
    if (ln == 0) {
        const int part = blockIdx.x*2 + (wv & 1);
        #pragma unroll
        for (int r = 0; r < 4; ++r) {
            const int row = row0 + wm + q*4 + r;
            *(float4*)&pmulv[(size_t)row*128 + part*4] =
                make_float4(pr[r][0], pr[r][1], pr[r][2], pr[r][3]);
        }
    }
}

// ---------------------------------------------------------------------------
// gemm3: decoder layer 1. Pre-phase: 256 threads reduce pmulv (8 thr/row)
// -> z in LDS; staging patch injects z into cols 0..1.
// ---------------------------------------------------------------------------
__global__ __launch_bounds__(256) void gemm_zfix(
    const __bf16* __restrict__ A, const __bf16* __restrict__ Wt,
    const float* __restrict__ bias, __bf16* __restrict__ C, int Kp,
    const float* __restrict__ pmulv, const float* __restrict__ bmu,
    const float* __restrict__ blv, const float* __restrict__ eps)
{
    __shared__ float zsh[32][2];
    const int tid = threadIdx.x;
    {
        const int row = tid >> 3, pg = tid & 7;      // 8 threads per row
        const int ra = blockIdx.y*32 + row;
        float4 s = make_float4(0.0f, 0.0f, 0.0f, 0.0f);
        #pragma unroll
        for (int p = pg*4; p < pg*4 + 4; ++p) {
            const float4 qa = *(const float4*)&pmulv[(size_t)ra*128 + p*4];
            s.x += qa.x; s.y += qa.y; s.z += qa.z; s.w += qa.w;
        }
        #pragma unroll
        for (int m = 1; m <= 4; m <<= 1) {
            s.x += __shfl_down(s.x, m);
            s.y += __shfl_down(s.y, m);
            s.z += __shfl_down(s.z, m);
            s.w += __shfl_down(s.w, m);
        }
        if (pg == 0) {
            zsh[row][0] = fmaf(expf(0.5f*(s.z + blv[0])), eps[ra*2+0], s.x + bmu[0]);
            zsh[row][1] = fmaf(expf(0.5f*(s.w + blv[1])), eps[ra*2+1], s.y + bmu[1]);
        }
    }
    __syncthreads();
    GEMM_CORE(A, Wt, Kp,
        if (ch == 0) {
            va[0] = (__bf16)zsh[r16][0];
            va[1] = (__bf16)zsh[r16][1];
            vb[0] = (__bf16)zsh[r16 + 16][0];
            vb[1] = (__bf16)zsh[r16 + 16][1];
        }
    )
    GEMM_WRITE_RELU(C)
}

// ---------------------------------------------------------------------------
// gemm4: decoder layer 2 + fused nn_out PARTIAL dots -> pnn[row][32][8].
// ---------------------------------------------------------------------------
__global__ __launch_bounds__(256) void gemm_out8(
    const __bf16* __restrict__ A, const __bf16* __restrict__ Wt,
    const float* __restrict__ bias, const float* __restrict__ w3,
    float* __restrict__ pnn, int Kp)
{
    const int tid = threadIdx.x;
    GEMM_CORE(A, Wt, Kp)
    const int c0 = col0 + wn + ln;
    const int c1 = c0 + 16;
    const float b0v = bias[c0], b1v = bias[c1];
    float pr[4][8];
    #pragma unroll
    for (int r = 0; r < 4; ++r) {
        const float h0 = fmaxf(acc0[r] + b0v, 0.0f);
        const float h1 = fmaxf(acc1[r] + b1v, 0.0f);
        #pragma unroll
        for (int j = 0; j < 8; ++j)
            pr[r][j] = fmaf(h0, w3[c0*8 + j], h1*w3[c1*8 + j]);
    }
    #pragma unroll
    for (int m = 1; m <= 8; m <<= 1)
        #pragma unroll
        for (int r = 0; r < 4; ++r)
            #pragma unroll
            for (int j = 0; j < 8; ++j)
                pr[r][j] += __shfl_xor(pr[r][j], m);
    if (ln == 0) {
        const int part = blockIdx.x*2 + (wv & 1);
        #pragma unroll
        for (int r = 0; r < 4; ++r) {
            const int row = row0 + wm + q*4 + r;
            *(float4*)&pnn[(size_t)row*256 + part*8] =
                make_float4(pr[r][0], pr[r][1], pr[r][2], pr[r][3]);
            *(float4*)&pnn[(size_t)row*256 + part*8 + 4] =
                make_float4(pr[r][4], pr[r][5], pr[r][6], pr[r][7]);
        }
    }
}

// ---------------------------------------------------------------------------
// ADMM solver — R16 verbatim (measured 59.8us best; dual-role lanes:
// same lanes do phase A then phase B — R20's disjoint-wave split serialized
// the phases and regressed to 86.8us).
// ---------------------------------------------------------------------------
#define DOT11(bb, a0, a1, a2) \
    fmaf(bb[0],a0.x, fmaf(bb[1],a0.y, fmaf(bb[2],a0.z, fmaf(bb[3],a0.w, \
    fmaf(bb[4],a1.x, fmaf(bb[5],a1.y, fmaf(bb[6],a1.z, fmaf(bb[7],a1.w, \
    fmaf(bb[8],a2.x, fmaf(bb[9],a2.y, bb[10]*a2.z))))))))))

__global__ __launch_bounds__(256) void solver_kernel(
    const float* __restrict__ pnn, const float* __restrict__ b3,
    const float* __restrict__ inp,
    const float* __restrict__ ise, const float* __restrict__ yub_p,
    const float* __restrict__ ylb_p,
    const float* __restrict__ Pg, const float* __restrict__ Pdg,
    const float* __restrict__ Pddg,
    const float* __restrict__ ws, float* __restrict__ out)
{
    __shared__ __align__(16) float sBcol[3][11][108];
    __shared__ float s_i2x[196], s_i2y[225], sR2x[121], sR2y[121];
    __shared__ __align__(16) float rows[7][104];
    __shared__ float dval[2][80];
    __shared__ __align__(16) float cxs[12], cys[12];
    __shared__ float wlin[24];
    __shared__ float obsS[4][10];
    __shared__ float nnS[8];

    const int tid = threadIdx.x;
    const int e = blockIdx.x;

    for (int i = tid; i < 3*11*108; i += 256) {
        const int mat = i / 1188, rem = i - mat*1188;
        const int k = rem / 108, t = rem - k*108;
        const float* G = (mat == 0) ? Pg : (mat == 1 ? Pdg : Pddg);
        sBcol[mat][k][t] = (t < NUMPT) ? G[t*NVAR + k] : 0.0f;
    }
    for (int i = tid; i < 196; i += 256) s_i2x[i] = ws[WS_INV2X + i];
    for (int i = tid; i < 225; i += 256) s_i2y[i] = ws[WS_INV2Y + i];
    for (int i = tid; i < 121; i += 256) { sR2x[i] = ws[WS_R2X + i]; sR2y[i] = ws[WS_R2Y + i]; }
    if (tid >= 112 && tid < 152) {
        const int i = tid - 112;
        obsS[i/10][i%10] = inp[e*INPD + 5 + (i/10) + 5*(i%10)];
    }
    if (tid >= 192) {   // nn_out = b3 + sum of 32 partials (parallel tree)
        const int l = tid - 192;
        const int j = l & 7, pg = l >> 3;
        float s = 0.0f;
        #pragma unroll
        for (int p = pg*4; p < pg*4 + 4; ++p)
            s += pnn[(size_t)e*256 + p*8 + j];
        s += __shfl_down(s, 8);
        s += __shfl_down(s, 16);
        s += __shfl_down(s, 32);
        if (pg == 0) nnS[j] = b3[j] + s;
    }
    if (tid >= 64 && tid < 92) {
        const int i = tid - 64;
        rows[i >> 2][100 + (i & 3)] = 0.0f;
    }
    if (tid == 92) cxs[11] = 0.0f;
    if (tid == 93) cys[11] = 0.0f;

    const bool isA = (tid < 200);
    const int tA = tid >> 1, hA2 = tid & 1;
    const bool isB = (tid < 154);
    const int hB = (tid >= 77) ? 1 : 0;
    const int dB = tid - 77*hB;
    const int rB = dB / 11, kB = dB - 11*rB;
    const int mB = (rB==1||rB==4) ? 2 : ((rB==2||rB==5) ? 1 : 0);
    const float* colp = &sBcol[mB][kB][hB*52];
    const float* rowp = &rows[rB][hB*52];

    float bP[NVAR], bQ[NVAR];
    if (isA) {
        const float* Qsrc = hA2 ? Pddg : Pdg;
        #pragma unroll
        for (int k = 0; k < NVAR; ++k) {
            bP[k] = Pg[tA*NVAR+k];
            bQ[k] = Qsrc[tA*NVAR+k];
        }
    }

    const float vx0 = ise[e*4 + 2], vy0 = ise[e*4 + 3];
    const float yub = yub_p[e], ylb = ylb_p[e];
    __syncthreads();

    const float DT = T_FIN_C / 99.0f;
    float xo[5], yo[5];
    if (isA) {
        const int ob0 = 5*hA2;
        #pragma unroll
        for (int o = 0; o < 5; ++o) {
            xo[o] = fmaf(obsS[2][ob0+o], tA*DT, obsS[0][ob0+o]);
            yo[o] = fmaf(obsS[3][ob0+o], tA*DT, obsS[1][ob0+o]);
        }
    }

    if (tid < 11) {
        float s = 0;
        #pragma unroll
        for (int c = 0; c < 4; ++c)
            s = fmaf(nnS[c], ws[WS_SVD + c*11 + tid], s);
        wlin[tid] = RHO_V_C * K_P_V_C * s;
    } else if (tid < 22) {
        const int k = tid - 11;
        float s = 0;
        #pragma unroll
        for (int c = 0; c < 4; ++c)
            s = fmaf(nnS[4 + c], ws[WS_SPD + c*11 + k], s);
        wlin[tid] = RHO_OFFSET_C * K_P_C * s;
    }
    __syncthreads();

    float lam = 0.0f, cb = 0.0f;
    if (tid < 11) {
        const int k = tid;
        float a = vx0 * ws[WS_INV1X + k*14 + 12];
        #pragma unroll
        for (int j = 0; j < NVAR; ++j)
            a = fmaf(-wlin[j], ws[WS_INV1X + k*14 + j], a);
        cb = a; cxs[k] = a;
    } else if (tid < 22) {
        const int k = tid - 11;
        float a = vy0 * ws[WS_INV1Y + k*15 + 12];
        #pragma unroll
        for (int j = 0; j < NVAR; ++j)
            a = fmaf(-wlin[11 + j], ws[WS_INV1Y + k*15 + j], a);
        cb = a; cys[k] = a;
    }
    __syncthreads();

    for (int it = 0; it < MAXIT; ++it) {
        if (isA) {
            const float4 x0 = *(const float4*)&cxs[0];
            const float4 x1 = *(const float4*)&cxs[4];
            const float4 x2 = *(const float4*)&cxs[8];
            const float4 y0 = *(const float4*)&cys[0];
            const float4 y1 = *(const float4*)&cys[4];
            const float4 y2 = *(const float4*)&cys[8];
            const float px = DOT11(bP, x0, x1, x2);
            const float py = DOT11(bP, y0, y1, y2);
            const float qx = DOT11(bQ, x0, x1, x2);
            const float qy = DOT11(bQ, y0, y1, y2);

            float srx = 0.0f, sry = 0.0f;
            #pragma unroll
            for (int o = 0; o < 5; ++o) {
                const float wc = px - xo[o], wsv = py - yo[o];
                const float aw = A_OBS_C * wsv, bw = B_OBS_C * wc;
                const float r2 = aw*aw + bw*bw;
                if (r2 > 0.0f) {
                    const float f = (r2 < ABSQ_C) ? (1.0f - AB_C * rsqrtf(r2)) : 0.0f;
                    srx = fmaf(wc, f, srx);
                    sry = fmaf(wsv, f, sry);
                } else {
                    srx -= A_OBS_C;
                }
            }
            const float mrx = srx + __shfl_xor(srx, 1);
            const float mry = sry + __shfl_xor(sry, 1);

            if (hA2 == 0) {
                rows[0][tA] = mrx;
                rows[3][tA] = mry;
                const float rv2 = qx*qx + qy*qy;
                float vxr, vyr;
                if (rv2 > 0.0f) {
                    const float ri = rsqrtf(rv2);
                    const float dv = fminf(fmaxf(rv2*ri, V_MIN_C), V_MAX_C);
                    const float f = 1.0f - dv*ri;
                    vxr = qx*f; vyr = qy*f;
                } else { vxr = -V_MIN_C; vyr = 0.0f; }
                rows[2][tA] = vxr;  rows[5][tA] = vyr;
                rows[6][tA] = fmaxf(0.0f, py - yub) - fmaxf(0.0f, ylb - py);
            } else {
                const float ra2 = qx*qx + qy*qy;
                float axr = 0.0f, ayr = 0.0f;
                if (ra2 > A_MAX_C*A_MAX_C) {
                    const float ri = rsqrtf(ra2);
                    const float f = 1.0f - A_MAX_C*ri;
                    axr = qx*f; ayr = qy*f;
                }
                rows[1][tA] = axr;  rows[4][tA] = ayr;
            }
        }
        __syncthreads();

        if (isB) {
            float s0 = 0.0f, s1 = 0.0f;
            #pragma unroll
            for (int i = 0; i < 13; ++i) {
                const float4 rr = *(const float4*)&rowp[i*4];
                const float4 cc = *(const float4*)&colp[i*4];
                s0 = fmaf(rr.x, cc.x, s0); s1 = fmaf(rr.y, cc.y, s1);
                s0 = fmaf(rr.z, cc.z, s0); s1 = fmaf(rr.w, cc.w, s1);
            }
            dval[hB][dB] = s0 + s1;
        }
        __syncthreads();

        if (tid < 22) {
            const int k = (tid < 11) ? tid : tid - 11;
            float u;
            if (tid < 11)
                u = RHO_OBS_C * ((dval[0][k]      + dval[1][k])
                               + (dval[0][11 + k] + dval[1][11 + k])
                               + (dval[0][22 + k] + dval[1][22 + k]));
            else
                u = RHO_OBS_C * ((dval[0][33 + k] + dval[1][33 + k])
                               + (dval[0][44 + k] + dval[1][44 + k])
                               + (dval[0][55 + k] + dval[1][55 + k])
                               + (dval[0][66 + k] + dval[1][66 + k]));
            wlin[tid] = 2.0f*u - lam - cb;
            lam -= u;
        }
        __builtin_amdgcn_wave_barrier();
        if (tid < 22) {
            const int k = (tid < 11) ? tid : tid - 11;
            if (tid < 11) {
                float a = vx0 * s_i2x[k*14 + 12];
                #pragma unroll
                for (int j = 0; j < NVAR; ++j) {
                    a = fmaf(-wlin[j], s_i2x[k*14 + j], a);
                    a = fmaf(sR2x[k*11 + j], cxs[j], a);
                }
                cxs[k] = a;
            } else {
                float a = vy0 * s_i2y[k*15 + 12];
                #pragma unroll
                for (int j = 0; j < NVAR; ++j) {
                    a = fmaf(-wlin[11 + j], s_i2y[k*15 + j], a);
                    a = fmaf(sR2y[k*11 + j], cys[j], a);
                }
                cys[k] = a;
            }
        }
        __syncthreads();
    }

    if (tid < NVAR) {
        out[e*22 + tid]      = cxs[tid];
        out[e*22 + 11 + tid] = cys[tid];
    }
}

// ---------------------------------------------------------------------------
extern "C" void kernel_launch(void* const* d_in, const int* in_sizes, int n_in,
                              void* d_out, int out_size, void* d_ws, size_t ws_size,
                              hipStream_t stream)
{
    (void)in_sizes; (void)n_in; (void)out_size; (void)ws_size;
    const float* inp    = (const float*)d_in[0];
    const float* ise    = (const float*)d_in[1];
    const float* traj   = (const float*)d_in[2];
    const float* yub    = (const float*)d_in[3];
    const float* ylb    = (const float*)d_in[4];
    const float* eps    = (const float*)d_in[5];
    const float* enc_w1 = (const float*)d_in[6];
    const float* enc_b1 = (const float*)d_in[7];
    const float* enc_w2 = (const float*)d_in[8];
    const float* enc_b2 = (const float*)d_in[9];
    const float* wmu    = (const float*)d_in[10];
    const float* bmu    = (const float*)d_in[11];
    const float* wlv    = (const float*)d_in[12];
    const float* blv    = (const float*)d_in[13];
    const float* dec_w1 = (const float*)d_in[14];
    const float* dec_b1 = (const float*)d_in[15];
    const float* dec_w2 = (const float*)d_in[16];
    const float* dec_b2 = (const float*)d_in[17];
    const float* dec_w3 = (const float*)d_in[18];
    const float* dec_b3 = (const float*)d_in[19];
    const float* P      = (const float*)d_in[20];
    const float* Pd     = (const float*)d_in[21];
    const float* Pdd    = (const float*)d_in[22];
    const float* mean   = (const float*)d_in[23];
    const float* stdv   = (const float*)d_in[24];

    float* ws    = (float*)d_ws;
    float* pmulv = ws + WS_BIG;                       // 1024 x 32 x 4
    float* pnn   = pmulv + (size_t)BATCH*128;         // 1024 x 32 x 8
    __bf16* bfb  = (__bf16*)(pnn + (size_t)BATCH*256);
    __bf16* enc_in = bfb;                             // 1024 x 256
    __bf16* dec_in = enc_in + (size_t)BATCH*256;      // 1024 x 128
    __bf16* hA     = dec_in + (size_t)BATCH*128;      // 1024 x 1024
    __bf16* wt1    = hA + (size_t)BATCH*HID;          // 1024 x 256
    __bf16* wt2    = wt1 + (size_t)HID*256;           // 1024 x 1024
    __bf16* wt3    = wt2 + (size_t)HID*HID;           // 1024 x 128
    __bf16* wt4    = wt3 + (size_t)HID*128;           // 1024 x 1024
    float* outf = (float*)d_out;

    setup_kernel<<<4 + 1024 + 608, 256, 0, stream>>>(
        P, Pd, Pdd, ws, inp, traj, mean, stdv, enc_in, dec_in,
        enc_w1, enc_w2, dec_w1, dec_w2, wt1, wt2, wt3, wt4);

    dim3 g(16, 32);   // 32x64 tiles -> 512 blocks -> 2 blocks/CU (best)
    gemm_relu<<<g, 256, 0, stream>>>(enc_in, wt1, enc_b1, hA, 256);
    gemm_mulv<<<g, 256, 0, stream>>>(hA, wt2, enc_b2, wmu, wlv, pmulv, 1024);
    gemm_zfix<<<g, 256, 0, stream>>>(dec_in, wt3, dec_b1, hA, 128,
                                     pmulv, bmu, blv, eps);
    gemm_out8<<<g, 256, 0, stream>>>(hA, wt4, dec_b2, dec_w3, pnn, 1024);
    solver_kernel<<<BATCH, 256, 0, stream>>>(pnn, dec_b3, inp, ise, yub, ylb,
                                             P, Pd, Pdd, ws, outf);
}